// Round 1
// baseline (131.182 us; speedup 1.0000x reference)
//
#include <hip/hip_runtime.h>
#include <math.h>

// EnvironmentLight shading: per-pixel SH degree-4 env light.
// Memory-bound: 92 useful B/pixel -> ~16us floor at ~6 TB/s.
// 4 pixels/thread so all (N,3) streams are 3x float4 per thread (16B/lane).
// `base` (25x3) is read with wave-uniform constant indices -> s_load/SGPRs.

__device__ __forceinline__ void shade_pixel(
    float px, float py, float pz,
    float nx, float ny, float nz,
    float ax, float ay, float az,
    float krv, float kmv,
    float vx, float vy, float vz,
    const float* __restrict__ eb, const float* __restrict__ fg_lut,
    float* rgb, float* dif, float* spc)
{
    // wo = safe_normalize(view_pos - gb_pos)
    float wx = vx - px, wy = vy - py, wz = vz - pz;
    float wl2 = wx*wx + wy*wy + wz*wz;
    float winv = 1.0f / sqrtf(fmaxf(wl2, 1e-20f));
    wx *= winv; wy *= winv; wz *= winv;

    float ndv = wx*nx + wy*ny + wz*nz;   // dot(wo, n); n is the RAW gb_normal

    // reflvec = safe_normalize(2*dot*n - wo)
    float rx = 2.0f*ndv*nx - wx;
    float ry = 2.0f*ndv*ny - wy;
    float rz = 2.0f*ndv*nz - wz;
    float rl2 = rx*rx + ry*ry + rz*rz;
    float rinv = 1.0f / sqrtf(fmaxf(rl2, 1e-20f));
    rx *= rinv; ry *= rinv; rz *= rinv;

    // ---- fg_lut bilinear, u=NdotV, v=kr, 256x256x2 fp32, clamp, texel-center ----
    float NdotV = fmaxf(ndv, 1e-4f);
    float xf = NdotV * 256.0f - 0.5f;
    float yf = krv   * 256.0f - 0.5f;
    float x0f = floorf(xf), y0f = floorf(yf);
    float fx = xf - x0f, fy = yf - y0f;
    int x0i = min(max((int)x0f, 0), 255);
    int x1i = min(x0i + 1, 255);
    int y0i = min(max((int)y0f, 0), 255);
    int y1i = min(y0i + 1, 255);
    const float2* lut2 = (const float2*)fg_lut;
    float2 t00 = lut2[(y0i << 8) + x0i];
    float2 t01 = lut2[(y0i << 8) + x1i];
    float2 t10 = lut2[(y1i << 8) + x0i];
    float2 t11 = lut2[(y1i << 8) + x1i];
    float gxw = 1.0f - fx, gyw = 1.0f - fy;
    float fg0 = (t00.x*gxw + t01.x*fx)*gyw + (t10.x*gxw + t11.x*fx)*fy;
    float fg1 = (t00.y*gxw + t01.y*fx)*gyw + (t10.y*gxw + t11.y*fx)*fy;

    // Gauss-Weierstrass band attenuation exp(-l(l+1)*kr^2), l(l+1) in {0,2,6,12,20}
    float k2 = krv*krv;
    float g1 = expf( -2.0f*k2);
    float g2 = expf( -6.0f*k2);
    float g3 = expf(-12.0f*k2);
    float g4 = expf(-20.0f*k2);

    // SH basis (degree 4) of reflvec, band weights folded in
    float xx = rx*rx, yy = ry*ry, zz = rz*rz;
    float xy = rx*ry, yz = ry*rz, xz = rx*rz;
    float b[25];
    b[0]  = 0.28209479177387814f;
    b[1]  = (-0.4886025119029199f*ry) * g1;
    b[2]  = ( 0.4886025119029199f*rz) * g1;
    b[3]  = (-0.4886025119029199f*rx) * g1;
    b[4]  = ( 1.0925484305920792f*xy) * g2;
    b[5]  = (-1.0925484305920792f*yz) * g2;
    b[6]  = ( 0.31539156525252005f*(2.0f*zz - xx - yy)) * g2;
    b[7]  = (-1.0925484305920792f*xz) * g2;
    b[8]  = ( 0.5462742152960396f*(xx - yy)) * g2;
    b[9]  = (-0.5900435899266435f*ry*(3.0f*xx - yy)) * g3;
    b[10] = ( 2.890611442640554f*xy*rz) * g3;
    b[11] = (-0.4570457994644658f*ry*(4.0f*zz - xx - yy)) * g3;
    b[12] = ( 0.3731763325901154f*rz*(2.0f*zz - 3.0f*xx - 3.0f*yy)) * g3;
    b[13] = (-0.4570457994644658f*rx*(4.0f*zz - xx - yy)) * g3;
    b[14] = ( 1.445305721320277f*rz*(xx - yy)) * g3;
    b[15] = (-0.5900435899266435f*rx*(xx - 3.0f*yy)) * g3;
    b[16] = ( 2.5033429417967046f*xy*(xx - yy)) * g4;
    b[17] = (-1.7701307697799304f*yz*(3.0f*xx - yy)) * g4;
    b[18] = ( 0.9461746957575601f*xy*(7.0f*zz - 1.0f)) * g4;
    b[19] = (-0.6690465435572892f*yz*(7.0f*zz - 3.0f)) * g4;
    b[20] = ( 0.10578554691520431f*(zz*(35.0f*zz - 30.0f) + 3.0f)) * g4;
    b[21] = (-0.6690465435572892f*xz*(7.0f*zz - 3.0f)) * g4;
    b[22] = ( 0.47308734787878004f*(xx - yy)*(7.0f*zz - 1.0f)) * g4;
    b[23] = (-1.7701307697799304f*xz*(xx - yy)) * g4;
    b[24] = ( 0.6258357354491761f*(xx*(xx - 3.0f*yy) - yy*(3.0f*xx - yy))) * g4;

    // diffuse quadratic form n_h^T M n_h, with M from RH constants (uses raw n)
    float q0  = nx*nx - ny*ny;
    float qz  = nz*nz;
    float qxy = nx*ny, qxz = nx*nz, qyz = ny*nz;

    float alb[3] = {ax, ay, az};
    #pragma unroll
    for (int c = 0; c < 3; ++c) {
        float e0 = eb[0*3+c], e1 = eb[1*3+c], e2 = eb[2*3+c], e3 = eb[3*3+c],
              e4 = eb[4*3+c], e5 = eb[5*3+c], e6 = eb[6*3+c], e7 = eb[7*3+c],
              e8 = eb[8*3+c];
        // M00 x^2 + M11 y^2 + M22 z^2 + M33 + 2(M01 xy + M02 xz + M03 x + M12 yz + M13 y + M23 z)
        float irr = 0.429043f*e8*q0 + 0.743125f*e6*qz + (0.886227f*e0 - 0.247708f*e6)
                  + 2.0f*(0.429043f*(e4*qxy + e7*qxz + e5*qyz)
                        + 0.511664f*(e3*nx + e1*ny + e2*nz));
        float dc = alb[c] * irr;

        float sr = 0.0f;
        #pragma unroll
        for (int k = 0; k < 25; ++k) sr += b[k] * eb[3*k + c];

        float F0 = (1.0f - kmv)*0.04f + alb[c]*kmv;
        float sc = sr * (F0*fg0 + fg1);

        float v = dc + sc;
        rgb[c] = 1.0f / (1.0f + expf(-v));
        dif[c] = dc;
        spc[c] = sc;
    }
}

__global__ __launch_bounds__(256) void shade_kernel(
    const float* __restrict__ gb_pos, const float* __restrict__ gb_normal,
    const float* __restrict__ albedo, const float* __restrict__ kr,
    const float* __restrict__ km, const float* __restrict__ view_pos,
    const float* __restrict__ base, const float* __restrict__ fg_lut,
    float* __restrict__ out, int N)
{
    int tid = blockIdx.x * blockDim.x + threadIdx.x;
    int p0 = tid * 4;
    if (p0 >= N) return;

    float* out_rgb = out;
    float* out_dif = out + (size_t)3 * N;
    float* out_spc = out + (size_t)6 * N;

    if (p0 + 4 <= N) {
        // fast path: 4 pixels -> 12 floats = exactly 3x float4 per (N,3) stream
        float P[12], Nr[12], A[12], V[12];
        const float4* pp = (const float4*)gb_pos    + 3*tid;
        const float4* qp = (const float4*)gb_normal + 3*tid;
        const float4* ap = (const float4*)albedo    + 3*tid;
        const float4* vp = (const float4*)view_pos  + 3*tid;
        #pragma unroll
        for (int j = 0; j < 3; ++j) {
            ((float4*)P )[j] = pp[j];
            ((float4*)Nr)[j] = qp[j];
            ((float4*)A )[j] = ap[j];
            ((float4*)V )[j] = vp[j];
        }
        float4 kr4 = ((const float4*)kr)[tid];
        float4 km4 = ((const float4*)km)[tid];
        float krs[4] = {kr4.x, kr4.y, kr4.z, kr4.w};
        float kms[4] = {km4.x, km4.y, km4.z, km4.w};

        float R[12], D[12], S[12];
        #pragma unroll
        for (int j = 0; j < 4; ++j) {
            shade_pixel(P[3*j], P[3*j+1], P[3*j+2],
                        Nr[3*j], Nr[3*j+1], Nr[3*j+2],
                        A[3*j], A[3*j+1], A[3*j+2],
                        krs[j], kms[j],
                        V[3*j], V[3*j+1], V[3*j+2],
                        base, fg_lut,
                        &R[3*j], &D[3*j], &S[3*j]);
        }
        #pragma unroll
        for (int j = 0; j < 3; ++j) {
            ((float4*)out_rgb)[3*tid + j] = ((float4*)R)[j];
            ((float4*)out_dif)[3*tid + j] = ((float4*)D)[j];
            ((float4*)out_spc)[3*tid + j] = ((float4*)S)[j];
        }
    } else {
        // tail (N not divisible by 4): scalar path
        for (int p = p0; p < N; ++p) {
            float R[3], D[3], S[3];
            shade_pixel(gb_pos[3*p], gb_pos[3*p+1], gb_pos[3*p+2],
                        gb_normal[3*p], gb_normal[3*p+1], gb_normal[3*p+2],
                        albedo[3*p], albedo[3*p+1], albedo[3*p+2],
                        kr[p], km[p],
                        view_pos[3*p], view_pos[3*p+1], view_pos[3*p+2],
                        base, fg_lut, R, D, S);
            for (int c = 0; c < 3; ++c) {
                out_rgb[3*p+c] = R[c];
                out_dif[3*p+c] = D[c];
                out_spc[3*p+c] = S[c];
            }
        }
    }
}

extern "C" void kernel_launch(void* const* d_in, const int* in_sizes, int n_in,
                              void* d_out, int out_size, void* d_ws, size_t ws_size,
                              hipStream_t stream) {
    const float* gb_pos    = (const float*)d_in[0];
    const float* gb_normal = (const float*)d_in[1];
    const float* albedo    = (const float*)d_in[2];
    // d_in[3] = ks: unused by the reference shade()
    const float* kr        = (const float*)d_in[4];
    const float* km        = (const float*)d_in[5];
    const float* view_pos  = (const float*)d_in[6];
    const float* base      = (const float*)d_in[7];
    const float* fg_lut    = (const float*)d_in[8];
    float* out = (float*)d_out;

    int N = in_sizes[0] / 3;           // gb_pos is (N,3)
    int nthreads = (N + 3) / 4;        // 4 pixels per thread
    int block = 256;
    int grid = (nthreads + block - 1) / block;
    shade_kernel<<<grid, block, 0, stream>>>(gb_pos, gb_normal, albedo, kr, km,
                                             view_pos, base, fg_lut, out, N);
}

// Round 2
// 128.565 us; speedup vs baseline: 1.0204x; 1.0204x over previous
//
#include <hip/hip_runtime.h>
#include <math.h>

// EnvironmentLight shading: per-pixel SH degree-4 env light.
// Memory-bound target: 92 useful B/pixel -> ~15us floor at 6.6 TB/s measured.
// R2: native transcendentals (__expf / v_rsq / v_rcp), fused SH accumulation
// (no b[25] live array -> lower VGPR pressure).

__device__ __forceinline__ void shade_pixel(
    float px, float py, float pz,
    float nx, float ny, float nz,
    float ax, float ay, float az,
    float krv, float kmv,
    float vx, float vy, float vz,
    const float* __restrict__ eb, const float* __restrict__ fg_lut,
    float* rgb, float* dif, float* spc)
{
    // wo = safe_normalize(view_pos - gb_pos)
    float wx = vx - px, wy = vy - py, wz = vz - pz;
    float wl2 = wx*wx + wy*wy + wz*wz;
    float winv = __builtin_amdgcn_rsqf(fmaxf(wl2, 1e-20f));
    wx *= winv; wy *= winv; wz *= winv;

    float ndv = wx*nx + wy*ny + wz*nz;   // dot(wo, n); n is the RAW gb_normal

    // reflvec = safe_normalize(2*dot*n - wo)
    float rx = 2.0f*ndv*nx - wx;
    float ry = 2.0f*ndv*ny - wy;
    float rz = 2.0f*ndv*nz - wz;
    float rl2 = rx*rx + ry*ry + rz*rz;
    float rinv = __builtin_amdgcn_rsqf(fmaxf(rl2, 1e-20f));
    rx *= rinv; ry *= rinv; rz *= rinv;

    // ---- fg_lut bilinear, u=NdotV, v=kr, 256x256x2 fp32, clamp, texel-center ----
    float NdotV = fmaxf(ndv, 1e-4f);
    float xf = NdotV * 256.0f - 0.5f;
    float yf = krv   * 256.0f - 0.5f;
    float x0f = floorf(xf), y0f = floorf(yf);
    float fx = xf - x0f, fy = yf - y0f;
    int x0i = min(max((int)x0f, 0), 255);
    int x1i = min(x0i + 1, 255);
    int y0i = min(max((int)y0f, 0), 255);
    int y1i = min(y0i + 1, 255);
    const float2* lut2 = (const float2*)fg_lut;
    float2 t00 = lut2[(y0i << 8) + x0i];
    float2 t01 = lut2[(y0i << 8) + x1i];
    float2 t10 = lut2[(y1i << 8) + x0i];
    float2 t11 = lut2[(y1i << 8) + x1i];
    float gxw = 1.0f - fx, gyw = 1.0f - fy;
    float fg0 = (t00.x*gxw + t01.x*fx)*gyw + (t10.x*gxw + t11.x*fx)*fy;
    float fg1 = (t00.y*gxw + t01.y*fx)*gyw + (t10.y*gxw + t11.y*fx)*fy;

    // Gauss-Weierstrass band attenuation exp(-l(l+1)*kr^2), l(l+1) in {2,6,12,20}
    float k2 = krv*krv;
    float g1 = __expf( -2.0f*k2);
    float g2 = __expf( -6.0f*k2);
    float g3 = __expf(-12.0f*k2);
    float g4 = __expf(-20.0f*k2);

    // SH basis of reflvec, band weight folded in, fused straight into the
    // three channel accumulators (no b[25] live array).
    float xx = rx*rx, yy = ry*ry, zz = rz*rz;
    float xy = rx*ry, yz = ry*rz, xz = rx*rz;

    float sr0 = 0.0f, sr1 = 0.0f, sr2 = 0.0f;
#define SHACC(K, EXPR) do { float bk_ = (EXPR);                      \
        sr0 = fmaf(bk_, eb[3*(K)+0], sr0);                           \
        sr1 = fmaf(bk_, eb[3*(K)+1], sr1);                           \
        sr2 = fmaf(bk_, eb[3*(K)+2], sr2); } while (0)

    SHACC(0,  0.28209479177387814f);
    SHACC(1,  (-0.4886025119029199f*ry) * g1);
    SHACC(2,  ( 0.4886025119029199f*rz) * g1);
    SHACC(3,  (-0.4886025119029199f*rx) * g1);
    SHACC(4,  ( 1.0925484305920792f*xy) * g2);
    SHACC(5,  (-1.0925484305920792f*yz) * g2);
    SHACC(6,  ( 0.31539156525252005f*(2.0f*zz - xx - yy)) * g2);
    SHACC(7,  (-1.0925484305920792f*xz) * g2);
    SHACC(8,  ( 0.5462742152960396f*(xx - yy)) * g2);
    SHACC(9,  (-0.5900435899266435f*ry*(3.0f*xx - yy)) * g3);
    SHACC(10, ( 2.890611442640554f*xy*rz) * g3);
    SHACC(11, (-0.4570457994644658f*ry*(4.0f*zz - xx - yy)) * g3);
    SHACC(12, ( 0.3731763325901154f*rz*(2.0f*zz - 3.0f*xx - 3.0f*yy)) * g3);
    SHACC(13, (-0.4570457994644658f*rx*(4.0f*zz - xx - yy)) * g3);
    SHACC(14, ( 1.445305721320277f*rz*(xx - yy)) * g3);
    SHACC(15, (-0.5900435899266435f*rx*(xx - 3.0f*yy)) * g3);
    SHACC(16, ( 2.5033429417967046f*xy*(xx - yy)) * g4);
    SHACC(17, (-1.7701307697799304f*yz*(3.0f*xx - yy)) * g4);
    SHACC(18, ( 0.9461746957575601f*xy*(7.0f*zz - 1.0f)) * g4);
    SHACC(19, (-0.6690465435572892f*yz*(7.0f*zz - 3.0f)) * g4);
    SHACC(20, ( 0.10578554691520431f*(zz*(35.0f*zz - 30.0f) + 3.0f)) * g4);
    SHACC(21, (-0.6690465435572892f*xz*(7.0f*zz - 3.0f)) * g4);
    SHACC(22, ( 0.47308734787878004f*(xx - yy)*(7.0f*zz - 1.0f)) * g4);
    SHACC(23, (-1.7701307697799304f*xz*(xx - yy)) * g4);
    SHACC(24, ( 0.6258357354491761f*(xx*(xx - 3.0f*yy) - yy*(3.0f*xx - yy))) * g4);
#undef SHACC

    // diffuse quadratic form n_h^T M n_h (uses raw n)
    float q0  = nx*nx - ny*ny;
    float qz  = nz*nz;
    float qxy = nx*ny, qxz = nx*nz, qyz = ny*nz;

    float alb[3] = {ax, ay, az};
    float srs[3] = {sr0, sr1, sr2};
    #pragma unroll
    for (int c = 0; c < 3; ++c) {
        float e0 = eb[0*3+c], e1 = eb[1*3+c], e2 = eb[2*3+c], e3 = eb[3*3+c],
              e4 = eb[4*3+c], e5 = eb[5*3+c], e6 = eb[6*3+c], e7 = eb[7*3+c],
              e8 = eb[8*3+c];
        float irr = 0.429043f*e8*q0 + 0.743125f*e6*qz + (0.886227f*e0 - 0.247708f*e6)
                  + 2.0f*(0.429043f*(e4*qxy + e7*qxz + e5*qyz)
                        + 0.511664f*(e3*nx + e1*ny + e2*nz));
        float dc = alb[c] * irr;

        float F0 = (1.0f - kmv)*0.04f + alb[c]*kmv;
        float sc = srs[c] * (F0*fg0 + fg1);

        float v = dc + sc;
        rgb[c] = __builtin_amdgcn_rcpf(1.0f + __expf(-v));
        dif[c] = dc;
        spc[c] = sc;
    }
}

__global__ __launch_bounds__(256) void shade_kernel(
    const float* __restrict__ gb_pos, const float* __restrict__ gb_normal,
    const float* __restrict__ albedo, const float* __restrict__ kr,
    const float* __restrict__ km, const float* __restrict__ view_pos,
    const float* __restrict__ base, const float* __restrict__ fg_lut,
    float* __restrict__ out, int N)
{
    int tid = blockIdx.x * blockDim.x + threadIdx.x;
    int p0 = tid * 4;
    if (p0 >= N) return;

    float* out_rgb = out;
    float* out_dif = out + (size_t)3 * N;
    float* out_spc = out + (size_t)6 * N;

    if (p0 + 4 <= N) {
        // fast path: 4 pixels -> 12 floats = exactly 3x float4 per (N,3) stream
        float P[12], Nr[12], A[12], V[12];
        const float4* pp = (const float4*)gb_pos    + 3*tid;
        const float4* qp = (const float4*)gb_normal + 3*tid;
        const float4* ap = (const float4*)albedo    + 3*tid;
        const float4* vp = (const float4*)view_pos  + 3*tid;
        #pragma unroll
        for (int j = 0; j < 3; ++j) {
            ((float4*)P )[j] = pp[j];
            ((float4*)Nr)[j] = qp[j];
            ((float4*)A )[j] = ap[j];
            ((float4*)V )[j] = vp[j];
        }
        float4 kr4 = ((const float4*)kr)[tid];
        float4 km4 = ((const float4*)km)[tid];
        float krs[4] = {kr4.x, kr4.y, kr4.z, kr4.w};
        float kms[4] = {km4.x, km4.y, km4.z, km4.w};

        float R[12], D[12], S[12];
        #pragma unroll
        for (int j = 0; j < 4; ++j) {
            shade_pixel(P[3*j], P[3*j+1], P[3*j+2],
                        Nr[3*j], Nr[3*j+1], Nr[3*j+2],
                        A[3*j], A[3*j+1], A[3*j+2],
                        krs[j], kms[j],
                        V[3*j], V[3*j+1], V[3*j+2],
                        base, fg_lut,
                        &R[3*j], &D[3*j], &S[3*j]);
        }
        #pragma unroll
        for (int j = 0; j < 3; ++j) {
            ((float4*)out_rgb)[3*tid + j] = ((float4*)R)[j];
            ((float4*)out_dif)[3*tid + j] = ((float4*)D)[j];
            ((float4*)out_spc)[3*tid + j] = ((float4*)S)[j];
        }
    } else {
        // tail (N not divisible by 4): scalar path
        for (int p = p0; p < N; ++p) {
            float R[3], D[3], S[3];
            shade_pixel(gb_pos[3*p], gb_pos[3*p+1], gb_pos[3*p+2],
                        gb_normal[3*p], gb_normal[3*p+1], gb_normal[3*p+2],
                        albedo[3*p], albedo[3*p+1], albedo[3*p+2],
                        kr[p], km[p],
                        view_pos[3*p], view_pos[3*p+1], view_pos[3*p+2],
                        base, fg_lut, R, D, S);
            for (int c = 0; c < 3; ++c) {
                out_rgb[3*p+c] = R[c];
                out_dif[3*p+c] = D[c];
                out_spc[3*p+c] = S[c];
            }
        }
    }
}

extern "C" void kernel_launch(void* const* d_in, const int* in_sizes, int n_in,
                              void* d_out, int out_size, void* d_ws, size_t ws_size,
                              hipStream_t stream) {
    const float* gb_pos    = (const float*)d_in[0];
    const float* gb_normal = (const float*)d_in[1];
    const float* albedo    = (const float*)d_in[2];
    // d_in[3] = ks: unused by the reference shade()
    const float* kr        = (const float*)d_in[4];
    const float* km        = (const float*)d_in[5];
    const float* view_pos  = (const float*)d_in[6];
    const float* base      = (const float*)d_in[7];
    const float* fg_lut    = (const float*)d_in[8];
    float* out = (float*)d_out;

    int N = in_sizes[0] / 3;           // gb_pos is (N,3)
    int nthreads = (N + 3) / 4;        // 4 pixels per thread
    int block = 256;
    int grid = (nthreads + block - 1) / block;
    shade_kernel<<<grid, block, 0, stream>>>(gb_pos, gb_normal, albedo, kr, km,
                                             view_pos, base, fg_lut, out, N);
}

// Round 3
// 123.200 us; speedup vs baseline: 1.0648x; 1.0435x over previous
//
#include <hip/hip_runtime.h>
#include <math.h>

// EnvironmentLight shading: per-pixel SH degree-4 env light.
// Memory floor: 94.7 MB total traffic -> ~15us at 6.5 TB/s measured.
// R3: LDS-staged 1 px/thread. Coalesced float4 global I/O via LDS round-trip;
// per-thread register footprint ~1 pixel -> ~2x occupancy vs 4px/thread for
// latency hiding of the random fg_lut gathers (L2-served, ~200cyc).

__device__ __forceinline__ void shade_pixel(
    float px, float py, float pz,
    float nx, float ny, float nz,
    float ax, float ay, float az,
    float krv, float kmv,
    float vx, float vy, float vz,
    const float* __restrict__ eb, const float* __restrict__ fg_lut,
    float* rgb, float* dif, float* spc)
{
    // wo = safe_normalize(view_pos - gb_pos)
    float wx = vx - px, wy = vy - py, wz = vz - pz;
    float wl2 = wx*wx + wy*wy + wz*wz;
    float winv = __builtin_amdgcn_rsqf(fmaxf(wl2, 1e-20f));
    wx *= winv; wy *= winv; wz *= winv;

    float ndv = wx*nx + wy*ny + wz*nz;   // dot(wo, n); n is the RAW gb_normal

    // reflvec = safe_normalize(2*dot*n - wo)
    float rx = 2.0f*ndv*nx - wx;
    float ry = 2.0f*ndv*ny - wy;
    float rz = 2.0f*ndv*nz - wz;
    float rl2 = rx*rx + ry*ry + rz*rz;
    float rinv = __builtin_amdgcn_rsqf(fmaxf(rl2, 1e-20f));
    rx *= rinv; ry *= rinv; rz *= rinv;

    // ---- fg_lut bilinear, u=NdotV, v=kr, 256x256x2 fp32, clamp, texel-center ----
    float NdotV = fmaxf(ndv, 1e-4f);
    float xf = NdotV * 256.0f - 0.5f;
    float yf = krv   * 256.0f - 0.5f;
    float x0f = floorf(xf), y0f = floorf(yf);
    float fx = xf - x0f, fy = yf - y0f;
    int x0i = min(max((int)x0f, 0), 255);
    int x1i = min(x0i + 1, 255);
    int y0i = min(max((int)y0f, 0), 255);
    int y1i = min(y0i + 1, 255);
    const float2* lut2 = (const float2*)fg_lut;
    float2 t00 = lut2[(y0i << 8) + x0i];
    float2 t01 = lut2[(y0i << 8) + x1i];
    float2 t10 = lut2[(y1i << 8) + x0i];
    float2 t11 = lut2[(y1i << 8) + x1i];
    float gxw = 1.0f - fx, gyw = 1.0f - fy;
    float fg0 = (t00.x*gxw + t01.x*fx)*gyw + (t10.x*gxw + t11.x*fx)*fy;
    float fg1 = (t00.y*gxw + t01.y*fx)*gyw + (t10.y*gxw + t11.y*fx)*fy;

    // Gauss-Weierstrass band attenuation exp(-l(l+1)*kr^2), l(l+1) in {2,6,12,20}
    float k2 = krv*krv;
    float g1 = __expf( -2.0f*k2);
    float g2 = __expf( -6.0f*k2);
    float g3 = __expf(-12.0f*k2);
    float g4 = __expf(-20.0f*k2);

    // SH basis of reflvec, band weight folded in, fused straight into the
    // three channel accumulators (no b[25] live array).
    float xx = rx*rx, yy = ry*ry, zz = rz*rz;
    float xy = rx*ry, yz = ry*rz, xz = rx*rz;

    float sr0 = 0.0f, sr1 = 0.0f, sr2 = 0.0f;
#define SHACC(K, EXPR) do { float bk_ = (EXPR);                      \
        sr0 = fmaf(bk_, eb[3*(K)+0], sr0);                           \
        sr1 = fmaf(bk_, eb[3*(K)+1], sr1);                           \
        sr2 = fmaf(bk_, eb[3*(K)+2], sr2); } while (0)

    SHACC(0,  0.28209479177387814f);
    SHACC(1,  (-0.4886025119029199f*ry) * g1);
    SHACC(2,  ( 0.4886025119029199f*rz) * g1);
    SHACC(3,  (-0.4886025119029199f*rx) * g1);
    SHACC(4,  ( 1.0925484305920792f*xy) * g2);
    SHACC(5,  (-1.0925484305920792f*yz) * g2);
    SHACC(6,  ( 0.31539156525252005f*(2.0f*zz - xx - yy)) * g2);
    SHACC(7,  (-1.0925484305920792f*xz) * g2);
    SHACC(8,  ( 0.5462742152960396f*(xx - yy)) * g2);
    SHACC(9,  (-0.5900435899266435f*ry*(3.0f*xx - yy)) * g3);
    SHACC(10, ( 2.890611442640554f*xy*rz) * g3);
    SHACC(11, (-0.4570457994644658f*ry*(4.0f*zz - xx - yy)) * g3);
    SHACC(12, ( 0.3731763325901154f*rz*(2.0f*zz - 3.0f*xx - 3.0f*yy)) * g3);
    SHACC(13, (-0.4570457994644658f*rx*(4.0f*zz - xx - yy)) * g3);
    SHACC(14, ( 1.445305721320277f*rz*(xx - yy)) * g3);
    SHACC(15, (-0.5900435899266435f*rx*(xx - 3.0f*yy)) * g3);
    SHACC(16, ( 2.5033429417967046f*xy*(xx - yy)) * g4);
    SHACC(17, (-1.7701307697799304f*yz*(3.0f*xx - yy)) * g4);
    SHACC(18, ( 0.9461746957575601f*xy*(7.0f*zz - 1.0f)) * g4);
    SHACC(19, (-0.6690465435572892f*yz*(7.0f*zz - 3.0f)) * g4);
    SHACC(20, ( 0.10578554691520431f*(zz*(35.0f*zz - 30.0f) + 3.0f)) * g4);
    SHACC(21, (-0.6690465435572892f*xz*(7.0f*zz - 3.0f)) * g4);
    SHACC(22, ( 0.47308734787878004f*(xx - yy)*(7.0f*zz - 1.0f)) * g4);
    SHACC(23, (-1.7701307697799304f*xz*(xx - yy)) * g4);
    SHACC(24, ( 0.6258357354491761f*(xx*(xx - 3.0f*yy) - yy*(3.0f*xx - yy))) * g4);
#undef SHACC

    // diffuse quadratic form n_h^T M n_h (uses raw n)
    float q0  = nx*nx - ny*ny;
    float qz  = nz*nz;
    float qxy = nx*ny, qxz = nx*nz, qyz = ny*nz;

    float alb[3] = {ax, ay, az};
    float srs[3] = {sr0, sr1, sr2};
    #pragma unroll
    for (int c = 0; c < 3; ++c) {
        float e0 = eb[0*3+c], e1 = eb[1*3+c], e2 = eb[2*3+c], e3 = eb[3*3+c],
              e4 = eb[4*3+c], e5 = eb[5*3+c], e6 = eb[6*3+c], e7 = eb[7*3+c],
              e8 = eb[8*3+c];
        float irr = 0.429043f*e8*q0 + 0.743125f*e6*qz + (0.886227f*e0 - 0.247708f*e6)
                  + 2.0f*(0.429043f*(e4*qxy + e7*qxz + e5*qyz)
                        + 0.511664f*(e3*nx + e1*ny + e2*nz));
        float dc = alb[c] * irr;

        float F0 = (1.0f - kmv)*0.04f + alb[c]*kmv;
        float sc = srs[c] * (F0*fg0 + fg1);

        float v = dc + sc;
        rgb[c] = __builtin_amdgcn_rcpf(1.0f + __expf(-v));
        dif[c] = dc;
        spc[c] = sc;
    }
}

__global__ __launch_bounds__(256) void shade_kernel(
    const float* __restrict__ gb_pos, const float* __restrict__ gb_normal,
    const float* __restrict__ albedo, const float* __restrict__ kr,
    const float* __restrict__ km, const float* __restrict__ view_pos,
    const float* __restrict__ base, const float* __restrict__ fg_lut,
    float* __restrict__ out, int N)
{
    // Per-block slice: 256 pixels. 768 floats per (N,3) stream = 192 float4.
    __shared__ float s_pos[768], s_nrm[768], s_alb[768], s_view[768];
    __shared__ float s_kr[256], s_km[256];

    const int t   = threadIdx.x;
    const int blk = blockIdx.x;
    const int p0  = blk << 8;           // first pixel of this block

    float* out_rgb = out;
    float* out_dif = out + (size_t)3 * N;
    float* out_spc = out + (size_t)6 * N;

    if (p0 + 256 <= N) {
        // ---- stage inputs: perfectly coalesced float4 ----
        if (t < 192) {
            const size_t b4 = (size_t)blk * 192 + t;
            ((float4*)s_pos )[t] = ((const float4*)gb_pos   )[b4];
            ((float4*)s_nrm )[t] = ((const float4*)gb_normal)[b4];
            ((float4*)s_alb )[t] = ((const float4*)albedo   )[b4];
            ((float4*)s_view)[t] = ((const float4*)view_pos )[b4];
        } else {
            const int u = t - 192;      // 64 threads for kr/km (64 float4 each)
            const size_t k4 = (size_t)blk * 64 + u;
            ((float4*)s_kr)[u] = ((const float4*)kr)[k4];
            ((float4*)s_km)[u] = ((const float4*)km)[k4];
        }
        __syncthreads();

        // ---- per-thread pixel read (stride-3 LDS = 2-way bank alias, free) ----
        float px = s_pos[3*t],  py = s_pos[3*t+1],  pz = s_pos[3*t+2];
        float nx = s_nrm[3*t],  ny = s_nrm[3*t+1],  nz = s_nrm[3*t+2];
        float ax = s_alb[3*t],  ay = s_alb[3*t+1],  az = s_alb[3*t+2];
        float vx = s_view[3*t], vy = s_view[3*t+1], vz = s_view[3*t+2];
        float krv = s_kr[t], kmv = s_km[t];
        __syncthreads();    // all reads done before outputs alias the input LDS

        float R[3], D[3], S[3];
        shade_pixel(px, py, pz, nx, ny, nz, ax, ay, az, krv, kmv,
                    vx, vy, vz, base, fg_lut, R, D, S);

        // ---- stage outputs into (reused) LDS ----
        s_pos[3*t] = R[0]; s_pos[3*t+1] = R[1]; s_pos[3*t+2] = R[2];
        s_nrm[3*t] = D[0]; s_nrm[3*t+1] = D[1]; s_nrm[3*t+2] = D[2];
        s_alb[3*t] = S[0]; s_alb[3*t+1] = S[1]; s_alb[3*t+2] = S[2];
        __syncthreads();

        if (t < 192) {
            const size_t b4 = (size_t)blk * 192 + t;
            ((float4*)out_rgb)[b4] = ((float4*)s_pos)[t];
            ((float4*)out_dif)[b4] = ((float4*)s_nrm)[t];
            ((float4*)out_spc)[b4] = ((float4*)s_alb)[t];
        }
    } else {
        // tail block (N not a multiple of 256): scalar path, no LDS
        const int p = p0 + t;
        if (p < N) {
            float R[3], D[3], S[3];
            shade_pixel(gb_pos[3*p], gb_pos[3*p+1], gb_pos[3*p+2],
                        gb_normal[3*p], gb_normal[3*p+1], gb_normal[3*p+2],
                        albedo[3*p], albedo[3*p+1], albedo[3*p+2],
                        kr[p], km[p],
                        view_pos[3*p], view_pos[3*p+1], view_pos[3*p+2],
                        base, fg_lut, R, D, S);
            for (int c = 0; c < 3; ++c) {
                out_rgb[3*p+c] = R[c];
                out_dif[3*p+c] = D[c];
                out_spc[3*p+c] = S[c];
            }
        }
    }
}

extern "C" void kernel_launch(void* const* d_in, const int* in_sizes, int n_in,
                              void* d_out, int out_size, void* d_ws, size_t ws_size,
                              hipStream_t stream) {
    const float* gb_pos    = (const float*)d_in[0];
    const float* gb_normal = (const float*)d_in[1];
    const float* albedo    = (const float*)d_in[2];
    // d_in[3] = ks: unused by the reference shade()
    const float* kr        = (const float*)d_in[4];
    const float* km        = (const float*)d_in[5];
    const float* view_pos  = (const float*)d_in[6];
    const float* base      = (const float*)d_in[7];
    const float* fg_lut    = (const float*)d_in[8];
    float* out = (float*)d_out;

    int N = in_sizes[0] / 3;           // gb_pos is (N,3)
    int block = 256;                   // 1 pixel per thread
    int grid = (N + block - 1) / block;
    shade_kernel<<<grid, block, 0, stream>>>(gb_pos, gb_normal, albedo, kr, km,
                                             view_pos, base, fg_lut, out, N);
}